// Round 1
// baseline (524.131 us; speedup 1.0000x reference)
//
#include <hip/hip_runtime.h>

// x: (T=128, B=4, E=10000, F=16) fp32, dummy_index d = 0.
// out: (128, 4, 10000, 15) fp32 = tanh(cumsum_T(x[...,1:] * dt)),
// dt[0] = t0+t1, dt[k] = t[k]-t[k-1], t = x[...,0].
//
// Mapping: 4 threads per (b,e) pair ("group"); each thread loads one float4
// (features 4*sub .. 4*sub+3) per timestep -> fully coalesced 16B/lane.
// Sub-lane 0's .x component is the dt channel; broadcast via __shfl to the
// other 3 lanes of the group. Sub 0 never stores its feature-0 accumulator.

#define TT   128
#define BE   40000            // B*E
#define X4_T 160000           // per-t stride in float4 units (B*E*F/4)
#define O_T  600000           // per-t stride in floats (B*E*15)

__device__ __forceinline__ float fast_tanh(float x) {
  // tanh(x) = 1 - 2/(exp(2x)+1); saturates correctly at +/-inf.
  float e = __expf(2.0f * x);          // v_exp_f32 + mul
  return 1.0f - __fdividef(2.0f, e + 1.0f);
}

__global__ __launch_bounds__(256) void integ_kernel(const float* __restrict__ x,
                                                    float* __restrict__ out) {
  const int gid  = blockIdx.x * 256 + threadIdx.x;   // grid sized exactly: 625*256 = 160000
  const int idx  = gid >> 2;                          // (b,e) group index, 0..39999
  const int sub  = gid & 3;                           // which float4 within F=16
  const int lane = threadIdx.x & 63;
  const int srcl = lane & ~3;                         // group leader lane (holds dt channel)

  const float4* xv = reinterpret_cast<const float4*>(x) + ((size_t)idx * 4 + sub);
  // Output base: feature index jo = 4*sub - 1 + c  (c = component 0..3).
  // For sub==0, c==0 would be jo = -1 -> guarded out (that's the dt channel).
  float* ob = out + (size_t)idx * 15 + (4 * sub - 1);

  // --- t = 0: dt = t[0] + t[1] (peek at t=1) ---
  float4 v0 = xv[0];
  float4 v1 = xv[(size_t)X4_T];
  float t0 = __shfl(v0.x, srcl, 64);
  float t1 = __shfl(v1.x, srcl, 64);

  float dt = t0 + t1;
  float a0 = v0.x * dt;
  float a1 = v0.y * dt;
  float a2 = v0.z * dt;
  float a3 = v0.w * dt;
  if (sub) ob[0] = fast_tanh(a0);
  ob[1] = fast_tanh(a1);
  ob[2] = fast_tanh(a2);
  ob[3] = fast_tanh(a3);

  // --- t = 1..127: dt = t[k] - t[k-1] ---
  float tprev = t0;
  float4 v = v1;
  for (int t = 1; t < TT; ++t) {
    // Prefetch next timestep (clamped to last valid t to stay in bounds;
    // the redundant reload on the final iteration is L2-hot and harmless).
    int tn = t + 1 < TT ? t + 1 : TT - 1;
    float4 vn = xv[(size_t)tn * X4_T];

    float tc = __shfl(v.x, srcl, 64);
    dt = tc - tprev;
    a0 = fmaf(v.x, dt, a0);
    a1 = fmaf(v.y, dt, a1);
    a2 = fmaf(v.z, dt, a2);
    a3 = fmaf(v.w, dt, a3);

    float* o = ob + (size_t)t * O_T;
    if (sub) o[0] = fast_tanh(a0);
    o[1] = fast_tanh(a1);
    o[2] = fast_tanh(a2);
    o[3] = fast_tanh(a3);

    tprev = tc;
    v = vn;
  }
}

extern "C" void kernel_launch(void* const* d_in, const int* in_sizes, int n_in,
                              void* d_out, int out_size, void* d_ws, size_t ws_size,
                              hipStream_t stream) {
  const float* x = (const float*)d_in[0];
  float* out = (float*)d_out;
  // 40000 groups * 4 threads = 160000 threads = 625 blocks of 256 exactly.
  integ_kernel<<<dim3(625), dim3(256), 0, stream>>>(x, out);
}